// Round 13
// baseline (287.184 us; speedup 1.0000x reference)
//
#include <hip/hip_runtime.h>
#include <hip/hip_bf16.h>
#include <math.h>

// Problem constants
constexpr int kB  = 8;
constexpr int kT  = 1024;
constexpr int kC  = 768;
constexpr int kNH = 12;
constexpr int kHD = 64;
constexpr int kM  = kB * kT;        // 8192 rows
constexpr int k3C = 3 * kC;         // 2304
constexpr int k4C = 4 * kC;         // 3072

typedef __bf16 bf16x8 __attribute__((ext_vector_type(8)));
typedef float  f32x4  __attribute__((ext_vector_type(4)));
typedef unsigned short u16x8 __attribute__((ext_vector_type(8)));

__device__ inline void gload_lds16(const void* g, void* l) {
  // async global->LDS, 16B per lane; LDS dest = wave-uniform base + lane*16
  __builtin_amdgcn_global_load_lds(
      (const __attribute__((address_space(1))) void*)g,
      (__attribute__((address_space(3))) void*)l, 16, 0, 0);
}

__device__ inline float ldx(const float* p) { return *p; }
__device__ inline float ldx(const __hip_bfloat16* p) { return __bfloat162float(*p); }

// ---------------------------------------------------------------------------
// LayerNorm: one block (256 threads) per row of 768. fp32/bf16 in, bf16 out.
// ---------------------------------------------------------------------------
template <typename TIN>
__global__ __launch_bounds__(256) void ln_kernel(
    const TIN* __restrict__ x, const float* __restrict__ g,
    const float* __restrict__ bta, __hip_bfloat16* __restrict__ out)
{
  __shared__ float red[4];
  int row = blockIdx.x;
  int tid = threadIdx.x;
  const TIN* xr = x + (size_t)row * kC;
  float v0 = ldx(xr + tid), v1 = ldx(xr + tid + 256), v2 = ldx(xr + tid + 512);

  float s = v0 + v1 + v2;
#pragma unroll
  for (int off = 32; off; off >>= 1) s += __shfl_xor(s, off);
  if ((tid & 63) == 0) red[tid >> 6] = s;
  __syncthreads();
  float mu = (red[0] + red[1] + red[2] + red[3]) * (1.0f / kC);

  float d0 = v0 - mu, d1 = v1 - mu, d2 = v2 - mu;
  float q = d0 * d0 + d1 * d1 + d2 * d2;
#pragma unroll
  for (int off = 32; off; off >>= 1) q += __shfl_xor(q, off);
  __syncthreads();
  if ((tid & 63) == 0) red[tid >> 6] = q;
  __syncthreads();
  float var = (red[0] + red[1] + red[2] + red[3]) * (1.0f / kC);
  float inv = rsqrtf(var + 1e-5f);

  __hip_bfloat16* orow = out + (size_t)row * kC;
  orow[tid]       = __float2bfloat16(d0 * inv * g[tid]       + bta[tid]);
  orow[tid + 256] = __float2bfloat16(d1 * inv * g[tid + 256] + bta[tid + 256]);
  orow[tid + 512] = __float2bfloat16(d2 * inv * g[tid + 512] + bta[tid + 512]);
}

// ---------------------------------------------------------------------------
// Weight transpose + cast: W[K][N] fp32 -> WT[N][K] bf16. 64x64 tiles.
// ---------------------------------------------------------------------------
__global__ __launch_bounds__(256) void transpose_cast(
    const float* __restrict__ W, __hip_bfloat16* __restrict__ WT, int K, int N)
{
  __shared__ __hip_bfloat16 t[64][65];
  int k0 = blockIdx.y * 64, n0 = blockIdx.x * 64;
  int tid = threadIdx.x;
#pragma unroll
  for (int it = 0; it < 16; ++it) {
    int e = it * 256 + tid;
    int r = e >> 6, c = e & 63;
    t[r][c] = __float2bfloat16(W[(size_t)(k0 + r) * N + n0 + c]);
  }
  __syncthreads();
#pragma unroll
  for (int it = 0; it < 16; ++it) {
    int e = it * 256 + tid;
    int nr = e >> 6, kc = e & 63;
    WT[(size_t)(n0 + nr) * K + k0 + kc] = t[kc][nr];
  }
}

// fast exact tanh-GELU: tanh(t) = 1 - 2/(e^{2t}+1), e^{2t} via exp2
__device__ inline float gelu_fast(float c) {
  float t = 0.7978845608028654f * (c + 0.044715f * c * c * c);
  float e = exp2f(t * 2.8853900817779268f);      // exp(2t)
  float th = 1.0f - 2.0f * __builtin_amdgcn_rcpf(e + 1.0f);
  return 0.5f * c * (1.0f + th);
}

// ---------------------------------------------------------------------------
// bf16 MFMA GEMM, 128x128 tile, BK=64, 4 waves (2x2), 2-phase dbuf
// (round-6 verified structure; round-11 unroll-2 + epilogue modes).
// MODE 0: bf16 out (qkv Q/K part); 2: bf16 out + gelu (fc);
//      3: +R fp32, bf16 out (proj->x1); 4: +R bf16, fp32 out (fc2->d_out);
//      5: bf16 out TRANSPOSED to Vt[b][h][d][t] (qkv V part; WT/bias
//         pre-offset by 1536 cols; packed 8B stores along t).
// ---------------------------------------------------------------------------
template <int MODE>
__global__ __launch_bounds__(256) void gemm_bf16(
    const __hip_bfloat16* __restrict__ A,   // [M][K] bf16
    const __hip_bfloat16* __restrict__ WT,  // [N][K] bf16
    const float* __restrict__ bias,         // [N] fp32
    const void* __restrict__ Rv,            // residual (fp32 MODE 3, bf16 MODE 4)
    void* __restrict__ outv, int M, int N, int K)
{
  __shared__ __align__(16) __hip_bfloat16 As[2][128 * 64];
  __shared__ __align__(16) __hip_bfloat16 Bs[2][128 * 64];
  const int tid  = threadIdx.x;
  const int lane = tid & 63, wid = tid >> 6;
  const int wr = wid >> 1, wc = wid & 1;
  const int r16 = lane & 15, g = lane >> 4;

  // XCD-aware bijective swizzle (nwg % 8 == 0 for all our grids)
  const int nwg = gridDim.x * gridDim.y;
  const int bid = blockIdx.y * gridDim.x + blockIdx.x;
  const int swz = (bid & 7) * (nwg >> 3) + (bid >> 3);
  const int m0 = (swz / gridDim.x) * 128;
  const int n0 = (swz % gridDim.x) * 128;

  const __hip_bfloat16* Abase = A  + (size_t)m0 * K;
  const __hip_bfloat16* Bbase = WT + (size_t)n0 * K;

  f32x4 acc[4][4] = {};

  auto stage = [&](int t, int buf) {
    const __hip_bfloat16* Ap = Abase + t * 64;
    const __hip_bfloat16* Bp = Bbase + t * 64;
#pragma unroll
    for (int it = 0; it < 4; ++it) {
      int e = it * 256 + tid;                 // chunk id 0..1023
      int row = e >> 3, ch = (e & 7) ^ (row & 7);
      char* la = (char*)&As[buf][0] + (it * 4096 + (tid & ~63) * 16);
      char* lb = (char*)&Bs[buf][0] + (it * 4096 + (tid & ~63) * 16);
      gload_lds16(Ap + (size_t)row * K + ch * 8, la);
      gload_lds16(Bp + (size_t)row * K + ch * 8, lb);
    }
  };

  auto compute = [&](const char* Ab, const char* Bb) {
#pragma unroll
    for (int s = 0; s < 2; ++s) {             // two k-steps of 32 within BK=64
      bf16x8 af[4], bf[4];
#pragma unroll
      for (int i = 0; i < 4; ++i) {
        int ar = wr * 64 + i * 16 + r16;
        af[i] = *(const bf16x8*)(Ab + ar * 128 + (((s * 4 + g) ^ (ar & 7)) << 4));
        int br = wc * 64 + i * 16 + r16;
        bf[i] = *(const bf16x8*)(Bb + br * 128 + (((s * 4 + g) ^ (br & 7)) << 4));
      }
#pragma unroll
      for (int i = 0; i < 4; ++i)
#pragma unroll
        for (int j = 0; j < 4; ++j)
          acc[i][j] = __builtin_amdgcn_mfma_f32_16x16x32_bf16(af[i], bf[j],
                                                              acc[i][j], 0, 0, 0);
    }
  };

  const int NT = K >> 6;                      // 12/24/48 — always even
  stage(0, 0);
  __syncthreads();                            // drains vmcnt -> tile 0 ready

  for (int t = 0; t < NT; t += 2) {
    stage(t + 1, 1);                          // in flight during compute(buf0)
    compute((const char*)&As[0][0], (const char*)&Bs[0][0]);
    __syncthreads();
    if (t + 2 < NT) stage(t + 2, 0);          // in flight during compute(buf1)
    compute((const char*)&As[1][0], (const char*)&Bs[1][0]);
    __syncthreads();
  }

  // epilogue: C/D layout col=lane&15, row=(lane>>4)*4+reg  [m89-verified]
  const int r0 = m0 + wr * 64 + g * 4;
  const int c0 = n0 + wc * 64 + r16;
#pragma unroll
  for (int i = 0; i < 4; ++i) {
#pragma unroll
    for (int j = 0; j < 4; ++j) {
      int col = c0 + j * 16;
      float bv = bias[col];
      if (MODE == 5) {
        // V part: write Vt[b][h][d][t], t = row; pack 4 consecutive t (8B)
        int hh = col >> 6, dd = col & 63;
        int rowb = r0 + i * 16;               // multiple of 4; block same b
        int bb = rowb >> 10, tr = rowb & 1023;
        __hip_bfloat16 t4[4];
#pragma unroll
        for (int q = 0; q < 4; ++q)
          t4[q] = __float2bfloat16(acc[i][j][q] + bv);
        __hip_bfloat16* vp = (__hip_bfloat16*)outv +
            ((size_t)(bb * kNH + hh) * kHD + dd) * kT + tr;
        *(uint2*)vp = *(const uint2*)t4;
      } else {
#pragma unroll
        for (int q = 0; q < 4; ++q) {
          int row = r0 + i * 16 + q;
          float c = acc[i][j][q] + bv;
          if (MODE == 3) {        // + fp32 residual, bf16 out (proj -> x1)
            c += ((const float*)Rv)[(size_t)row * N + col];
            ((__hip_bfloat16*)outv)[(size_t)row * N + col] = __float2bfloat16(c);
          } else if (MODE == 4) { // + bf16 residual, fp32 out (fc2 -> d_out)
            c += __bfloat162float(((const __hip_bfloat16*)Rv)[(size_t)row * N + col]);
            ((float*)outv)[(size_t)row * N + col] = c;
          } else {
            if (MODE == 2) c = gelu_fast(c);
            ((__hip_bfloat16*)outv)[(size_t)row * N + col] = __float2bfloat16(c);
          }
        }
      }
    }
  }
}

// ---------------------------------------------------------------------------
// MFMA flash attention, fixed-shift softmax (verified r5), dbuf K/V (r12),
// VALU-trimmed (r13):
//  - all 16 P-write LDS addresses hoisted to registers (loop-invariant)
//  - staging global pointers advanced per tile (no per-tile recompute)
//  - mask folded into exp2 argument: p = exp2(fma(s,kSc,mb)), mb in {0,-2e4}
//    (exp2 underflow -> exact 0 for masked keys)
// ---------------------------------------------------------------------------
__global__ __launch_bounds__(256) void attn_mfma(
    const __hip_bfloat16* __restrict__ qkv,
    const __hip_bfloat16* __restrict__ vt,
    const int* __restrict__ mask,
    __hip_bfloat16* __restrict__ o)
{
  __shared__ __align__(16) __hip_bfloat16 Ks[2][64 * 64];
  __shared__ __align__(16) __hip_bfloat16 Vs[2][64 * 64];
  __shared__ __align__(16) __hip_bfloat16 Ps[4 * 16 * 64];

  const int b = blockIdx.z, h = blockIdx.y, q0 = blockIdx.x * 64;
  const int tid = threadIdx.x, lane = tid & 63, wid = tid >> 6;
  const int r16 = lane & 15, g = lane >> 4;
  const size_t rs = k3C;
  const __hip_bfloat16* qb = qkv + (size_t)(b * kT) * rs + h * kHD;
  const __hip_bfloat16* kb = qb + kC;
  const __hip_bfloat16* vtb = vt + (size_t)(b * kNH + h) * kHD * kT;
  const int* mrow = mask + b * kT;
  constexpr float kSc = 0.125f * 1.4426950408889634f;  // 0.125 * log2(e)

  // ---- prologue: hoist all loop-invariant state into registers ----
  // staging source pointers (advance per tile) and fixed LDS dests
  const __hip_bfloat16* kg[2];
  const __hip_bfloat16* vg[2];
  char* lk[2][2]; char* lv[2][2];
#pragma unroll
  for (int it = 0; it < 2; ++it) {
    int e = it * 256 + tid;
    int row = e >> 3, ch = (e & 7) ^ (row & 7);
    kg[it] = kb + (size_t)row * rs + ch * 8;          // += 64*rs per tile
    vg[it] = vtb + (size_t)row * kT + ch * 8;         // += 64 per tile
#pragma unroll
    for (int buf = 0; buf < 2; ++buf) {
      lk[buf][it] = (char*)&Ks[buf][0] + (it * 4096 + (tid & ~63) * 16);
      lv[buf][it] = (char*)&Vs[buf][0] + (it * 4096 + (tid & ~63) * 16);
    }
  }
  // P-write addresses (16, static-indexed -> registers)
  __hip_bfloat16* Pw = Ps + wid * 1024;
  __hip_bfloat16* paddr[4][4];
#pragma unroll
  for (int r = 0; r < 4; ++r) {
    int q = g * 4 + r;
    char* pwq = (char*)Pw + q * 128 + (r16 & 7) * 2;
#pragma unroll
    for (int j = 0; j < 4; ++j) {
      int chn = ((j << 1) | (r16 >> 3)) ^ (q & 7);
      paddr[r][j] = (__hip_bfloat16*)(pwq + (chn << 4));
    }
  }
  // Q fragments
  bf16x8 qf[2];
  {
    const __hip_bfloat16* qr = qb + (size_t)(q0 + wid * 16 + r16) * rs;
#pragma unroll
    for (int s = 0; s < 2; ++s) qf[s] = *(const bf16x8*)(qr + s * 32 + g * 8);
  }
  // mask bitmask: bit t*4+j = mask[t*64+16j+r16]
  unsigned long long km = 0;
#pragma unroll
  for (int t = 0; t < 16; ++t)
#pragma unroll
    for (int j = 0; j < 4; ++j)
      if (mrow[t * 64 + 16 * j + r16] != 0)
        km |= 1ull << (t * 4 + j);

  // stage tile 0
  gload_lds16(kg[0], lk[0][0]); gload_lds16(vg[0], lv[0][0]);
  gload_lds16(kg[1], lk[0][1]); gload_lds16(vg[1], lv[0][1]);
  __syncthreads();             // tile 0 ready (vmcnt drained)

  f32x4 o_acc[4] = {};          // db: d = 16*db + r16 ; reg: q = g*4 + reg
  float l_part[4] = {0.f, 0.f, 0.f, 0.f};

  for (int t = 0; t < 16; ++t) {
    const int buf = t & 1;
    kg[0] += 64 * rs; kg[1] += 64 * rs; vg[0] += 64; vg[1] += 64;
    if (t + 1 < 16) {           // next tile in flight under this tile's compute
      gload_lds16(kg[0], lk[buf ^ 1][0]); gload_lds16(vg[0], lv[buf ^ 1][0]);
      gload_lds16(kg[1], lk[buf ^ 1][1]); gload_lds16(vg[1], lv[buf ^ 1][1]);
    }

    const char* Kb = (const char*)&Ks[buf][0];
    const char* Vb = (const char*)&Vs[buf][0];

    // S = Q K^T : 4 key-blocks x 2 k-steps
    f32x4 sa[4] = {};
#pragma unroll
    for (int j = 0; j < 4; ++j) {
#pragma unroll
      for (int s = 0; s < 2; ++s) {
        int kr = 16 * j + r16;
        bf16x8 kf = *(const bf16x8*)(Kb + kr * 128 +
                                     (((s * 4 + g) ^ (kr & 7)) << 4));
        sa[j] = __builtin_amdgcn_mfma_f32_16x16x32_bf16(qf[s], kf, sa[j], 0, 0, 0);
      }
    }

    // softmax numerator: p = exp2(fma(s, kSc, mb)); masked -> exact 0
    float mb[4];
#pragma unroll
    for (int j = 0; j < 4; ++j)
      mb[j] = ((km >> (t * 4 + j)) & 1ull) ? 0.f : -20000.f;
#pragma unroll
    for (int r = 0; r < 4; ++r) {
      float p[4];
#pragma unroll
      for (int j = 0; j < 4; ++j)
        p[j] = exp2f(fmaf(sa[j][r], kSc, mb[j]));
      l_part[r] += (p[0] + p[1]) + (p[2] + p[3]);
#pragma unroll
      for (int j = 0; j < 4; ++j)
        *paddr[r][j] = __float2bfloat16(p[j]);
    }

    asm volatile("s_waitcnt lgkmcnt(0)" ::: "memory");  // P writes visible (wave)
    __builtin_amdgcn_sched_barrier(0);

    // O += P @ Vt
#pragma unroll
    for (int s = 0; s < 2; ++s) {
      bf16x8 pf = *(const bf16x8*)((const char*)Pw + r16 * 128 +
                                   (((s * 4 + g) ^ (r16 & 7)) << 4));
#pragma unroll
      for (int db = 0; db < 4; ++db) {
        int vr = 16 * db + r16;
        bf16x8 vf = *(const bf16x8*)(Vb + vr * 128 +
                                     (((s * 4 + g) ^ (vr & 7)) << 4));
        o_acc[db] = __builtin_amdgcn_mfma_f32_16x16x32_bf16(pf, vf, o_acc[db], 0, 0, 0);
      }
    }
    __syncthreads();   // all waves done with buf; next tile (buf^1) landed
  }

#pragma unroll
  for (int r = 0; r < 4; ++r) {
    float l = l_part[r];
#pragma unroll
    for (int off = 8; off; off >>= 1) l += __shfl_xor(l, off);
    float inv = 1.f / l;
    size_t row = (size_t)(b * kT) + q0 + wid * 16 + g * 4 + r;
#pragma unroll
    for (int db = 0; db < 4; ++db)
      o[row * kC + h * kHD + 16 * db + r16] = __float2bfloat16(o_acc[db][r] * inv);
  }
}

// ---------------------------------------------------------------------------
// Launch
// ---------------------------------------------------------------------------
extern "C" void kernel_launch(void* const* d_in, const int* in_sizes, int n_in,
                              void* d_out, int out_size, void* d_ws, size_t ws_size,
                              hipStream_t stream) {
  const float* x      = (const float*)d_in[0];
  const int*   amask  = (const int*)  d_in[1];
  const float* ln1_g  = (const float*)d_in[2];
  const float* ln1_b  = (const float*)d_in[3];
  const float* W_attn = (const float*)d_in[4];
  const float* b_attn = (const float*)d_in[5];
  const float* W_proj = (const float*)d_in[6];
  const float* b_proj = (const float*)d_in[7];
  const float* ln2_g  = (const float*)d_in[8];
  const float* ln2_b  = (const float*)d_in[9];
  const float* W_fc   = (const float*)d_in[10];
  const float* b_fc   = (const float*)d_in[11];
  const float* W_fc2  = (const float*)d_in[12];
  const float* b_fc2  = (const float*)d_in[13];
  float* out = (float*)d_out;

  // workspace layout (bytes):
  //   [0, 12.6MB)      h / o / h2  bf16
  //   [16MB, 66.3MB)   qkv bf16 (37.7MB) / fc bf16 (50.3MB) overlay
  //   [68MB..84MB)     transposed bf16 weights
  //   [84MB, 96.6MB)   Vt bf16 (until attn) / x1 bf16 (after proj) overlay
  char* ws = (char*)d_ws;
  __hip_bfloat16* h_bf    = (__hip_bfloat16*)(ws);
  __hip_bfloat16* qkv_bf  = (__hip_bfloat16*)(ws + (size_t)16 * 1024 * 1024);
  __hip_bfloat16* fc_bf   = qkv_bf;
  __hip_bfloat16* wt_attn = (__hip_bfloat16*)(ws + (size_t)68 * 1024 * 1024);
  __hip_bfloat16* wt_proj = (__hip_bfloat16*)(ws + (size_t)72 * 1024 * 1024);
  __hip_bfloat16* wt_fc   = (__hip_bfloat16*)(ws + (size_t)74 * 1024 * 1024);
  __hip_bfloat16* wt_fc2  = (__hip_bfloat16*)(ws + (size_t)79 * 1024 * 1024);
  __hip_bfloat16* vt_bf   = (__hip_bfloat16*)(ws + (size_t)84 * 1024 * 1024);
  __hip_bfloat16* x1_bf   = vt_bf;   // Vt dead after attn; x1 reuses it

  dim3 blk(256);

  // 0. weight transpose+cast
  transpose_cast<<<dim3(k3C / 64, kC / 64), blk, 0, stream>>>(W_attn, wt_attn, kC, k3C);
  transpose_cast<<<dim3(kC / 64, kC / 64), blk, 0, stream>>>(W_proj, wt_proj, kC, kC);
  transpose_cast<<<dim3(k4C / 64, kC / 64), blk, 0, stream>>>(W_fc, wt_fc, kC, k4C);
  transpose_cast<<<dim3(kC / 64, k4C / 64), blk, 0, stream>>>(W_fc2, wt_fc2, k4C, kC);

  // 1. h = LN1(x)
  ln_kernel<float><<<kM, blk, 0, stream>>>(x, ln1_g, ln1_b, h_bf);
  // 2a. qkv Q/K part: cols 0..1535   (12x64 = 768 blocks)
  gemm_bf16<0><<<dim3(12, kM / 128), blk, 0, stream>>>(
      h_bf, wt_attn, b_attn, nullptr, qkv_bf, kM, k3C, kC);
  // 2b. qkv V part -> Vt directly    (6x64 = 384 blocks)
  gemm_bf16<5><<<dim3(6, kM / 128), blk, 0, stream>>>(
      h_bf, wt_attn + (size_t)(2 * kC) * kC, b_attn + 2 * kC, nullptr,
      vt_bf, kM, kC, kC);
  // 3. o = attention (overwrites h)
  attn_mfma<<<dim3(kT / 64, kNH, kB), blk, 0, stream>>>(qkv_bf, vt_bf, amask, h_bf);
  // 4. x1 = x + o @ W_proj + b_proj -> bf16 (6x64 = 384 blocks)
  gemm_bf16<3><<<dim3(kC / 128, kM / 128), blk, 0, stream>>>(
      h_bf, wt_proj, b_proj, x, x1_bf, kM, kC, kC);
  // 5. h2 = LN2(x1)  (bf16 in)
  ln_kernel<__hip_bfloat16><<<kM, blk, 0, stream>>>(x1_bf, ln2_g, ln2_b, h_bf);
  // 6. fc = gelu(h2 @ W_fc + b_fc)   (24x64 = 1536 blocks)
  gemm_bf16<2><<<dim3(k4C / 128, kM / 128), blk, 0, stream>>>(
      h_bf, wt_fc, b_fc, nullptr, fc_bf, kM, k4C, kC);
  // 7. out = x1 + fc @ W_fc2 + b_fc2  -> fp32 d_out (6x64 = 384 blocks)
  gemm_bf16<4><<<dim3(kC / 128, kM / 128), blk, 0, stream>>>(
      fc_bf, wt_fc2, b_fc2, x1_bf, out, kM, kC, k4C);
}

// Round 14
// 280.814 us; speedup vs baseline: 1.0227x; 1.0227x over previous
//
#include <hip/hip_runtime.h>
#include <hip/hip_bf16.h>
#include <math.h>

// Problem constants
constexpr int kB  = 8;
constexpr int kT  = 1024;
constexpr int kC  = 768;
constexpr int kNH = 12;
constexpr int kHD = 64;
constexpr int kM  = kB * kT;        // 8192 rows
constexpr int k3C = 3 * kC;         // 2304
constexpr int k4C = 4 * kC;         // 3072

typedef __bf16 bf16x8 __attribute__((ext_vector_type(8)));
typedef float  f32x4  __attribute__((ext_vector_type(4)));
typedef unsigned short u16x8 __attribute__((ext_vector_type(8)));

__device__ inline void gload_lds16(const void* g, void* l) {
  // async global->LDS, 16B per lane; LDS dest = wave-uniform base + lane*16
  __builtin_amdgcn_global_load_lds(
      (const __attribute__((address_space(1))) void*)g,
      (__attribute__((address_space(3))) void*)l, 16, 0, 0);
}

__device__ inline float ldx(const float* p) { return *p; }
__device__ inline float ldx(const __hip_bfloat16* p) { return __bfloat162float(*p); }

// ---------------------------------------------------------------------------
// LayerNorm: one block (256 threads) per row of 768. fp32/bf16 in, bf16 out.
// ---------------------------------------------------------------------------
template <typename TIN>
__global__ __launch_bounds__(256) void ln_kernel(
    const TIN* __restrict__ x, const float* __restrict__ g,
    const float* __restrict__ bta, __hip_bfloat16* __restrict__ out)
{
  __shared__ float red[4];
  int row = blockIdx.x;
  int tid = threadIdx.x;
  const TIN* xr = x + (size_t)row * kC;
  float v0 = ldx(xr + tid), v1 = ldx(xr + tid + 256), v2 = ldx(xr + tid + 512);

  float s = v0 + v1 + v2;
#pragma unroll
  for (int off = 32; off; off >>= 1) s += __shfl_xor(s, off);
  if ((tid & 63) == 0) red[tid >> 6] = s;
  __syncthreads();
  float mu = (red[0] + red[1] + red[2] + red[3]) * (1.0f / kC);

  float d0 = v0 - mu, d1 = v1 - mu, d2 = v2 - mu;
  float q = d0 * d0 + d1 * d1 + d2 * d2;
#pragma unroll
  for (int off = 32; off; off >>= 1) q += __shfl_xor(q, off);
  __syncthreads();
  if ((tid & 63) == 0) red[tid >> 6] = q;
  __syncthreads();
  float var = (red[0] + red[1] + red[2] + red[3]) * (1.0f / kC);
  float inv = rsqrtf(var + 1e-5f);

  __hip_bfloat16* orow = out + (size_t)row * kC;
  orow[tid]       = __float2bfloat16(d0 * inv * g[tid]       + bta[tid]);
  orow[tid + 256] = __float2bfloat16(d1 * inv * g[tid + 256] + bta[tid + 256]);
  orow[tid + 512] = __float2bfloat16(d2 * inv * g[tid + 512] + bta[tid + 512]);
}

// ---------------------------------------------------------------------------
// Weight transpose + cast: W[K][N] fp32 -> WT[N][K] bf16. 64x64 tiles.
// ---------------------------------------------------------------------------
__global__ __launch_bounds__(256) void transpose_cast(
    const float* __restrict__ W, __hip_bfloat16* __restrict__ WT, int K, int N)
{
  __shared__ __hip_bfloat16 t[64][65];
  int k0 = blockIdx.y * 64, n0 = blockIdx.x * 64;
  int tid = threadIdx.x;
#pragma unroll
  for (int it = 0; it < 16; ++it) {
    int e = it * 256 + tid;
    int r = e >> 6, c = e & 63;
    t[r][c] = __float2bfloat16(W[(size_t)(k0 + r) * N + n0 + c]);
  }
  __syncthreads();
#pragma unroll
  for (int it = 0; it < 16; ++it) {
    int e = it * 256 + tid;
    int nr = e >> 6, kc = e & 63;
    WT[(size_t)(n0 + nr) * K + k0 + kc] = t[kc][nr];
  }
}

// fast exact tanh-GELU: tanh(t) = 1 - 2/(e^{2t}+1), e^{2t} via exp2
__device__ inline float gelu_fast(float c) {
  float t = 0.7978845608028654f * (c + 0.044715f * c * c * c);
  float e = exp2f(t * 2.8853900817779268f);      // exp(2t)
  float th = 1.0f - 2.0f * __builtin_amdgcn_rcpf(e + 1.0f);
  return 0.5f * c * (1.0f + th);
}

// ---------------------------------------------------------------------------
// bf16 MFMA GEMM, 128x128 tile, BK=64, 4 waves (2x2), 2-phase dbuf
// (round-6 verified structure; round-11 unroll-2 + epilogue modes).
// MODE 0: bf16 out; 2: bf16 out + gelu (fc);
//      3: +R fp32, bf16 out (proj->x1); 4: +R bf16, fp32 out (fc2->d_out);
//      5: bf16 out TRANSPOSED to Vt[b][h][d][t] (qkv V part).
// ---------------------------------------------------------------------------
template <int MODE>
__global__ __launch_bounds__(256) void gemm_bf16(
    const __hip_bfloat16* __restrict__ A,   // [M][K] bf16
    const __hip_bfloat16* __restrict__ WT,  // [N][K] bf16
    const float* __restrict__ bias,         // [N] fp32
    const void* __restrict__ Rv,            // residual (fp32 MODE 3, bf16 MODE 4)
    void* __restrict__ outv, int M, int N, int K)
{
  __shared__ __align__(16) __hip_bfloat16 As[2][128 * 64];
  __shared__ __align__(16) __hip_bfloat16 Bs[2][128 * 64];
  const int tid  = threadIdx.x;
  const int lane = tid & 63, wid = tid >> 6;
  const int wr = wid >> 1, wc = wid & 1;
  const int r16 = lane & 15, g = lane >> 4;

  // XCD-aware bijective swizzle (nwg % 8 == 0 for all our grids)
  const int nwg = gridDim.x * gridDim.y;
  const int bid = blockIdx.y * gridDim.x + blockIdx.x;
  const int swz = (bid & 7) * (nwg >> 3) + (bid >> 3);
  const int m0 = (swz / gridDim.x) * 128;
  const int n0 = (swz % gridDim.x) * 128;

  const __hip_bfloat16* Abase = A  + (size_t)m0 * K;
  const __hip_bfloat16* Bbase = WT + (size_t)n0 * K;

  f32x4 acc[4][4] = {};

  auto stage = [&](int t, int buf) {
    const __hip_bfloat16* Ap = Abase + t * 64;
    const __hip_bfloat16* Bp = Bbase + t * 64;
#pragma unroll
    for (int it = 0; it < 4; ++it) {
      int e = it * 256 + tid;                 // chunk id 0..1023
      int row = e >> 3, ch = (e & 7) ^ (row & 7);
      char* la = (char*)&As[buf][0] + (it * 4096 + (tid & ~63) * 16);
      char* lb = (char*)&Bs[buf][0] + (it * 4096 + (tid & ~63) * 16);
      gload_lds16(Ap + (size_t)row * K + ch * 8, la);
      gload_lds16(Bp + (size_t)row * K + ch * 8, lb);
    }
  };

  auto compute = [&](const char* Ab, const char* Bb) {
#pragma unroll
    for (int s = 0; s < 2; ++s) {             // two k-steps of 32 within BK=64
      bf16x8 af[4], bf[4];
#pragma unroll
      for (int i = 0; i < 4; ++i) {
        int ar = wr * 64 + i * 16 + r16;
        af[i] = *(const bf16x8*)(Ab + ar * 128 + (((s * 4 + g) ^ (ar & 7)) << 4));
        int br = wc * 64 + i * 16 + r16;
        bf[i] = *(const bf16x8*)(Bb + br * 128 + (((s * 4 + g) ^ (br & 7)) << 4));
      }
#pragma unroll
      for (int i = 0; i < 4; ++i)
#pragma unroll
        for (int j = 0; j < 4; ++j)
          acc[i][j] = __builtin_amdgcn_mfma_f32_16x16x32_bf16(af[i], bf[j],
                                                              acc[i][j], 0, 0, 0);
    }
  };

  const int NT = K >> 6;                      // 12/24/48 — always even
  stage(0, 0);
  __syncthreads();                            // drains vmcnt -> tile 0 ready

  for (int t = 0; t < NT; t += 2) {
    stage(t + 1, 1);                          // in flight during compute(buf0)
    compute((const char*)&As[0][0], (const char*)&Bs[0][0]);
    __syncthreads();
    if (t + 2 < NT) stage(t + 2, 0);          // in flight during compute(buf1)
    compute((const char*)&As[1][0], (const char*)&Bs[1][0]);
    __syncthreads();
  }

  // epilogue: C/D layout col=lane&15, row=(lane>>4)*4+reg  [m89-verified]
  const int r0 = m0 + wr * 64 + g * 4;
  const int c0 = n0 + wc * 64 + r16;
#pragma unroll
  for (int i = 0; i < 4; ++i) {
#pragma unroll
    for (int j = 0; j < 4; ++j) {
      int col = c0 + j * 16;
      float bv = bias[col];
      if (MODE == 5) {
        // V part: write Vt[b][h][d][t], t = row; pack 4 consecutive t (8B)
        int hh = col >> 6, dd = col & 63;
        int rowb = r0 + i * 16;               // multiple of 4; block same b
        int bb = rowb >> 10, tr = rowb & 1023;
        __hip_bfloat16 t4[4];
#pragma unroll
        for (int q = 0; q < 4; ++q)
          t4[q] = __float2bfloat16(acc[i][j][q] + bv);
        __hip_bfloat16* vp = (__hip_bfloat16*)outv +
            ((size_t)(bb * kNH + hh) * kHD + dd) * kT + tr;
        *(uint2*)vp = *(const uint2*)t4;
      } else {
#pragma unroll
        for (int q = 0; q < 4; ++q) {
          int row = r0 + i * 16 + q;
          float c = acc[i][j][q] + bv;
          if (MODE == 3) {        // + fp32 residual, bf16 out (proj -> x1)
            c += ((const float*)Rv)[(size_t)row * N + col];
            ((__hip_bfloat16*)outv)[(size_t)row * N + col] = __float2bfloat16(c);
          } else if (MODE == 4) { // + bf16 residual, fp32 out (fc2 -> d_out)
            c += __bfloat162float(((const __hip_bfloat16*)Rv)[(size_t)row * N + col]);
            ((float*)outv)[(size_t)row * N + col] = c;
          } else {
            if (MODE == 2) c = gelu_fast(c);
            ((__hip_bfloat16*)outv)[(size_t)row * N + col] = __float2bfloat16(c);
          }
        }
      }
    }
  }
}

// ---------------------------------------------------------------------------
// MFMA flash attention, fixed-shift softmax (r5), dbuf K/V (r12), VALU-trim
// (r13), now 8 waves / 512 threads / QBLK=128 (r14): per-wave code identical
// (wave owns 16 q-rows); 3 blocks/CU x 8 waves = 24 waves/CU for latency
// hiding (was 29% occupancy at 4 waves). Grid 768 = exactly 3/CU.
// LDS: Ks 2x8K + Vs 2x8K + Ps 16K = 48KB.
// ---------------------------------------------------------------------------
__global__ __launch_bounds__(512) void attn_mfma(
    const __hip_bfloat16* __restrict__ qkv,
    const __hip_bfloat16* __restrict__ vt,
    const int* __restrict__ mask,
    __hip_bfloat16* __restrict__ o)
{
  __shared__ __align__(16) __hip_bfloat16 Ks[2][64 * 64];
  __shared__ __align__(16) __hip_bfloat16 Vs[2][64 * 64];
  __shared__ __align__(16) __hip_bfloat16 Ps[8 * 16 * 64];

  const int b = blockIdx.z, h = blockIdx.y, q0 = blockIdx.x * 128;
  const int tid = threadIdx.x, lane = tid & 63, wid = tid >> 6;
  const int r16 = lane & 15, g = lane >> 4;
  const size_t rs = k3C;
  const __hip_bfloat16* qb = qkv + (size_t)(b * kT) * rs + h * kHD;
  const __hip_bfloat16* kb = qb + kC;
  const __hip_bfloat16* vtb = vt + (size_t)(b * kNH + h) * kHD * kT;
  const int* mrow = mask + b * kT;
  constexpr float kSc = 0.125f * 1.4426950408889634f;  // 0.125 * log2(e)

  // ---- prologue: hoist loop-invariant state ----
  // staging: 512 threads cover the 512 chunks of each 64x64 tile exactly
  const __hip_bfloat16* kg;
  const __hip_bfloat16* vg;
  char* lk[2]; char* lv[2];
  {
    int row = tid >> 3, ch = (tid & 7) ^ (row & 7);
    kg = kb + (size_t)row * rs + ch * 8;              // += 64*rs per tile
    vg = vtb + (size_t)row * kT + ch * 8;             // += 64 per tile
#pragma unroll
    for (int buf = 0; buf < 2; ++buf) {
      lk[buf] = (char*)&Ks[buf][0] + (tid & ~63) * 16;
      lv[buf] = (char*)&Vs[buf][0] + (tid & ~63) * 16;
    }
  }
  // P-write addresses (16, static-indexed -> registers)
  __hip_bfloat16* Pw = Ps + wid * 1024;
  __hip_bfloat16* paddr[4][4];
#pragma unroll
  for (int r = 0; r < 4; ++r) {
    int q = g * 4 + r;
    char* pwq = (char*)Pw + q * 128 + (r16 & 7) * 2;
#pragma unroll
    for (int j = 0; j < 4; ++j) {
      int chn = ((j << 1) | (r16 >> 3)) ^ (q & 7);
      paddr[r][j] = (__hip_bfloat16*)(pwq + (chn << 4));
    }
  }
  // Q fragments
  bf16x8 qf[2];
  {
    const __hip_bfloat16* qr = qb + (size_t)(q0 + wid * 16 + r16) * rs;
#pragma unroll
    for (int s = 0; s < 2; ++s) qf[s] = *(const bf16x8*)(qr + s * 32 + g * 8);
  }
  // mask bitmask: bit t*4+j = mask[t*64+16j+r16]
  unsigned long long km = 0;
#pragma unroll
  for (int t = 0; t < 16; ++t)
#pragma unroll
    for (int j = 0; j < 4; ++j)
      if (mrow[t * 64 + 16 * j + r16] != 0)
        km |= 1ull << (t * 4 + j);

  // stage tile 0
  gload_lds16(kg, lk[0]); gload_lds16(vg, lv[0]);
  __syncthreads();             // tile 0 ready (vmcnt drained)

  f32x4 o_acc[4] = {};          // db: d = 16*db + r16 ; reg: q = g*4 + reg
  float l_part[4] = {0.f, 0.f, 0.f, 0.f};

  for (int t = 0; t < 16; ++t) {
    const int buf = t & 1;
    kg += 64 * rs; vg += 64;
    if (t + 1 < 16) {           // next tile in flight under this tile's compute
      gload_lds16(kg, lk[buf ^ 1]); gload_lds16(vg, lv[buf ^ 1]);
    }

    const char* Kb = (const char*)&Ks[buf][0];
    const char* Vb = (const char*)&Vs[buf][0];

    // S = Q K^T : 4 key-blocks x 2 k-steps
    f32x4 sa[4] = {};
#pragma unroll
    for (int j = 0; j < 4; ++j) {
#pragma unroll
      for (int s = 0; s < 2; ++s) {
        int kr = 16 * j + r16;
        bf16x8 kf = *(const bf16x8*)(Kb + kr * 128 +
                                     (((s * 4 + g) ^ (kr & 7)) << 4));
        sa[j] = __builtin_amdgcn_mfma_f32_16x16x32_bf16(qf[s], kf, sa[j], 0, 0, 0);
      }
    }

    // softmax numerator: p = exp2(fma(s, kSc, mb)); masked -> exact 0
    float mb[4];
#pragma unroll
    for (int j = 0; j < 4; ++j)
      mb[j] = ((km >> (t * 4 + j)) & 1ull) ? 0.f : -20000.f;
#pragma unroll
    for (int r = 0; r < 4; ++r) {
      float p[4];
#pragma unroll
      for (int j = 0; j < 4; ++j)
        p[j] = exp2f(fmaf(sa[j][r], kSc, mb[j]));
      l_part[r] += (p[0] + p[1]) + (p[2] + p[3]);
#pragma unroll
      for (int j = 0; j < 4; ++j)
        *paddr[r][j] = __float2bfloat16(p[j]);
    }

    asm volatile("s_waitcnt lgkmcnt(0)" ::: "memory");  // P writes visible (wave)
    __builtin_amdgcn_sched_barrier(0);

    // O += P @ Vt
#pragma unroll
    for (int s = 0; s < 2; ++s) {
      bf16x8 pf = *(const bf16x8*)((const char*)Pw + r16 * 128 +
                                   (((s * 4 + g) ^ (r16 & 7)) << 4));
#pragma unroll
      for (int db = 0; db < 4; ++db) {
        int vr = 16 * db + r16;
        bf16x8 vf = *(const bf16x8*)(Vb + vr * 128 +
                                     (((s * 4 + g) ^ (vr & 7)) << 4));
        o_acc[db] = __builtin_amdgcn_mfma_f32_16x16x32_bf16(pf, vf, o_acc[db], 0, 0, 0);
      }
    }
    __syncthreads();   // all waves done with buf; next tile (buf^1) landed
  }

#pragma unroll
  for (int r = 0; r < 4; ++r) {
    float l = l_part[r];
#pragma unroll
    for (int off = 8; off; off >>= 1) l += __shfl_xor(l, off);
    float inv = 1.f / l;
    size_t row = (size_t)(b * kT) + q0 + wid * 16 + g * 4 + r;
#pragma unroll
    for (int db = 0; db < 4; ++db)
      o[row * kC + h * kHD + 16 * db + r16] = __float2bfloat16(o_acc[db][r] * inv);
  }
}

// ---------------------------------------------------------------------------
// Launch
// ---------------------------------------------------------------------------
extern "C" void kernel_launch(void* const* d_in, const int* in_sizes, int n_in,
                              void* d_out, int out_size, void* d_ws, size_t ws_size,
                              hipStream_t stream) {
  const float* x      = (const float*)d_in[0];
  const int*   amask  = (const int*)  d_in[1];
  const float* ln1_g  = (const float*)d_in[2];
  const float* ln1_b  = (const float*)d_in[3];
  const float* W_attn = (const float*)d_in[4];
  const float* b_attn = (const float*)d_in[5];
  const float* W_proj = (const float*)d_in[6];
  const float* b_proj = (const float*)d_in[7];
  const float* ln2_g  = (const float*)d_in[8];
  const float* ln2_b  = (const float*)d_in[9];
  const float* W_fc   = (const float*)d_in[10];
  const float* b_fc   = (const float*)d_in[11];
  const float* W_fc2  = (const float*)d_in[12];
  const float* b_fc2  = (const float*)d_in[13];
  float* out = (float*)d_out;

  // workspace layout (bytes):
  //   [0, 12.6MB)      h / o / h2  bf16
  //   [16MB, 66.3MB)   qkv bf16 (37.7MB) / fc bf16 (50.3MB) overlay
  //   [68MB..84MB)     transposed bf16 weights
  //   [84MB, 96.6MB)   Vt bf16 (until attn) / x1 bf16 (after proj) overlay
  char* ws = (char*)d_ws;
  __hip_bfloat16* h_bf    = (__hip_bfloat16*)(ws);
  __hip_bfloat16* qkv_bf  = (__hip_bfloat16*)(ws + (size_t)16 * 1024 * 1024);
  __hip_bfloat16* fc_bf   = qkv_bf;
  __hip_bfloat16* wt_attn = (__hip_bfloat16*)(ws + (size_t)68 * 1024 * 1024);
  __hip_bfloat16* wt_proj = (__hip_bfloat16*)(ws + (size_t)72 * 1024 * 1024);
  __hip_bfloat16* wt_fc   = (__hip_bfloat16*)(ws + (size_t)74 * 1024 * 1024);
  __hip_bfloat16* wt_fc2  = (__hip_bfloat16*)(ws + (size_t)79 * 1024 * 1024);
  __hip_bfloat16* vt_bf   = (__hip_bfloat16*)(ws + (size_t)84 * 1024 * 1024);
  __hip_bfloat16* x1_bf   = vt_bf;   // Vt dead after attn; x1 reuses it

  dim3 blk(256);

  // 0. weight transpose+cast
  transpose_cast<<<dim3(k3C / 64, kC / 64), blk, 0, stream>>>(W_attn, wt_attn, kC, k3C);
  transpose_cast<<<dim3(kC / 64, kC / 64), blk, 0, stream>>>(W_proj, wt_proj, kC, kC);
  transpose_cast<<<dim3(k4C / 64, kC / 64), blk, 0, stream>>>(W_fc, wt_fc, kC, k4C);
  transpose_cast<<<dim3(kC / 64, k4C / 64), blk, 0, stream>>>(W_fc2, wt_fc2, k4C, kC);

  // 1. h = LN1(x)
  ln_kernel<float><<<kM, blk, 0, stream>>>(x, ln1_g, ln1_b, h_bf);
  // 2a. qkv Q/K part: cols 0..1535   (12x64 = 768 blocks)
  gemm_bf16<0><<<dim3(12, kM / 128), blk, 0, stream>>>(
      h_bf, wt_attn, b_attn, nullptr, qkv_bf, kM, k3C, kC);
  // 2b. qkv V part -> Vt directly    (6x64 = 384 blocks)
  gemm_bf16<5><<<dim3(6, kM / 128), blk, 0, stream>>>(
      h_bf, wt_attn + (size_t)(2 * kC) * kC, b_attn + 2 * kC, nullptr,
      vt_bf, kM, kC, kC);
  // 3. o = attention (overwrites h)   (8x12x8 = 768 blocks, 512 thr)
  attn_mfma<<<dim3(kT / 128, kNH, kB), dim3(512), 0, stream>>>(
      qkv_bf, vt_bf, amask, h_bf);
  // 4. x1 = x + o @ W_proj + b_proj -> bf16 (6x64 = 384 blocks)
  gemm_bf16<3><<<dim3(kC / 128, kM / 128), blk, 0, stream>>>(
      h_bf, wt_proj, b_proj, x, x1_bf, kM, kC, kC);
  // 5. h2 = LN2(x1)  (bf16 in)
  ln_kernel<__hip_bfloat16><<<kM, blk, 0, stream>>>(x1_bf, ln2_g, ln2_b, h_bf);
  // 6. fc = gelu(h2 @ W_fc + b_fc)   (24x64 = 1536 blocks)
  gemm_bf16<2><<<dim3(k4C / 128, kM / 128), blk, 0, stream>>>(
      h_bf, wt_fc, b_fc, nullptr, fc_bf, kM, k4C, kC);
  // 7. out = x1 + fc @ W_fc2 + b_fc2  -> fp32 d_out (6x64 = 384 blocks)
  gemm_bf16<4><<<dim3(kC / 128, kM / 128), blk, 0, stream>>>(
      fc_bf, wt_fc2, b_fc2, x1_bf, out, kM, kC, k4C);
}